// Round 3
// baseline (251.329 us; speedup 1.0000x reference)
//
#include <hip/hip_runtime.h>
#include <hip/hip_bf16.h>
#include <math.h>

#define MEM 2048
#define NF4 512   // float4 per 2048-row

__device__ __forceinline__ float dot4(float4 a, float4 b) {
    return a.x * b.x + a.y * b.y + a.z * b.z + a.w * b.w;
}

__device__ __forceinline__ float wave_reduce(float v) {
#pragma unroll
    for (int off = 32; off > 0; off >>= 1)
        v += __shfl_down(v, off, 64);
    return v;
}

__device__ __forceinline__ float sigmoidf_(float x) {
    return 1.0f / (1.0f + expf(-x));
}

// ws layout (floats):
//  slot0 [0*2048): dwl (k1)  -> overwritten by la (k_mid)
//  slot1 [1*2048): dwr (k1)  -> overwritten by ra (k_mid)
//  slot2 [2*2048): dus (k1)  -> overwritten by part[m=0] (k2)
//  slot3 [3*2048): pl  (k1)  -> overwritten by part[m=1] (k2)
//  slot4 [4*2048): pr  (k1)  -> overwritten by part[m=2] (k2)
//  slot5..9      : part[m=3..7] (k2)
// total 10*2048 floats = 80 KB.

// k1: gridDim=(256,3). blockIdx.y: 0=Wh, 1=Us, 2=ma. Each block reads ONE
// contiguous 64KB slab (8 rows) of its matrix; 2 rows per wave; dots with
// x1 (and x2). Raw dots only — biases/tanh deferred to k_mid.
__global__ __launch_bounds__(256) void
k1_slab(const float* __restrict__ lh, const float* __restrict__ rh,
        const float* __restrict__ S,
        const float* __restrict__ Wh_w, const float* __restrict__ Us_w,
        const float* __restrict__ ma_w,
        float* __restrict__ ws)
{
    __shared__ __align__(16) float s_x1[MEM];
    __shared__ __align__(16) float s_x2[MEM];

    const int t  = threadIdx.x;
    const int m  = blockIdx.y;
    const int rg = blockIdx.x;

    const float* W  = (m == 0) ? Wh_w : (m == 1) ? Us_w : ma_w;
    const float* x1 = (m == 1) ? S : lh;
    const float* x2 = (m == 1) ? S : rh;

    {
        const float4* a4 = (const float4*)x1;
        const float4* b4 = (const float4*)x2;
        float4* s14 = (float4*)s_x1;
        float4* s24 = (float4*)s_x2;
        for (int i = t; i < NF4; i += 256) { s14[i] = a4[i]; s24[i] = b4[i]; }
    }
    __syncthreads();

    const int wv = t >> 6, ln = t & 63;
    const int row0 = rg * 8 + wv * 2;

    const float4* __restrict__ w0 = (const float4*)(W + (size_t)row0 * MEM);
    const float4* __restrict__ w1 = w0 + NF4;
    const float4* sx1 = (const float4*)s_x1;
    const float4* sx2 = (const float4*)s_x2;

    float a00 = 0.f, a01 = 0.f, a10 = 0.f, a11 = 0.f;
#pragma unroll
    for (int i = 0; i < 8; ++i) {
        const int idx = i * 64 + ln;
        const float4 wa = w0[idx];
        const float4 wb = w1[idx];
        const float4 p  = sx1[idx];
        const float4 q  = sx2[idx];
        a00 += dot4(wa, p); a01 += dot4(wa, q);
        a10 += dot4(wb, p); a11 += dot4(wb, q);
    }
    a00 = wave_reduce(a00); a01 = wave_reduce(a01);
    a10 = wave_reduce(a10); a11 = wave_reduce(a11);

    if (ln == 0) {
        if (m == 0) {            // Wh: dwl = W·lh, dwr = W·rh
            ws[row0] = a00; ws[row0 + 1] = a10;
            ws[MEM + row0] = a01; ws[MEM + row0 + 1] = a11;
        } else if (m == 1) {     // Us: dus = W·S
            ws[2 * MEM + row0] = a00; ws[2 * MEM + row0 + 1] = a10;
        } else {                 // ma: pl = W·lh, pr = W·rh
            ws[3 * MEM + row0] = a00; ws[3 * MEM + row0 + 1] = a10;
            ws[4 * MEM + row0] = a01; ws[4 * MEM + row0 + 1] = a11;
        }
    }
}

// k_mid: ONE block. alpha from raw dots, then la/ra into ws slots 0/1.
__global__ __launch_bounds__(1024) void
k_mid(const float* __restrict__ w, const float* __restrict__ Wh_b,
      const float* __restrict__ Us_b, const float* __restrict__ ma_b,
      float* __restrict__ ws)
{
    __shared__ float s_red[16][2];
    __shared__ float s_al[2];

    const int t = threadIdx.x;
    float el = 0.f, er = 0.f;
    for (int j = t; j < MEM; j += 1024) {
        const float us = ws[2 * MEM + j] + Us_b[j];
        const float bb = Wh_b[j] + us;
        const float ml = tanhf(ws[j] + bb);
        const float mr = tanhf(ws[MEM + j] + bb);
        const float wj = w[j];
        el += wj * ml; er += wj * mr;
    }
    el = wave_reduce(el);
    er = wave_reduce(er);
    const int wv = t >> 6, ln = t & 63;
    if (ln == 0) { s_red[wv][0] = el; s_red[wv][1] = er; }
    __syncthreads();
    if (t == 0) {
        float e0 = 0.f, e1 = 0.f;
#pragma unroll
        for (int k = 0; k < 16; ++k) { e0 += s_red[k][0]; e1 += s_red[k][1]; }
        const float d = e0 + e1;
        s_al[0] = e0 / d;
        s_al[1] = e1 / d;
    }
    __syncthreads();
    const float al = s_al[0];
    const float ar = s_al[1];
    for (int j = t; j < MEM; j += 1024) {
        const float mb = ma_b[j];
        const float la = tanhf(al * ws[3 * MEM + j] + mb);
        const float ra = tanhf(ar * ws[4 * MEM + j] + mb);
        ws[j] = la;          // safe: this thread's dwl[j]/dwr[j] consumed pre-barrier
        ws[MEM + j] = ra;
    }
}

// k2: gridDim=(256,8). blockIdx.y = gate-matrix m (even→la, odd→ra).
// Each block: one contiguous 64KB slab (8 rows), 2 rows/wave, pure stream.
__global__ __launch_bounds__(256) void
k2_slab(const float* __restrict__ ilh_w,  const float* __restrict__ irh_w,
        const float* __restrict__ lflh_w, const float* __restrict__ lfrh_w,
        const float* __restrict__ rflh_w, const float* __restrict__ rfrh_w,
        const float* __restrict__ ulh_w,  const float* __restrict__ urh_w,
        float* __restrict__ ws)
{
    __shared__ __align__(16) float s_x[MEM];

    const int t  = threadIdx.x;
    const int m  = blockIdx.y;
    const int rg = blockIdx.x;

    const float* Wt[8] = {ilh_w, irh_w, lflh_w, lfrh_w, rflh_w, rfrh_w, ulh_w, urh_w};
    const float* W = Wt[m];
    const float* x = ws + (size_t)(m & 1) * MEM;   // even=la, odd=ra

    {
        const float4* x4 = (const float4*)x;
        float4* s4 = (float4*)s_x;
        for (int i = t; i < NF4; i += 256) s4[i] = x4[i];
    }
    __syncthreads();

    const int wv = t >> 6, ln = t & 63;
    const int row0 = rg * 8 + wv * 2;

    const float4* __restrict__ w0 = (const float4*)(W + (size_t)row0 * MEM);
    const float4* __restrict__ w1 = w0 + NF4;
    const float4* sx = (const float4*)s_x;

    float a0 = 0.f, a1 = 0.f;
#pragma unroll
    for (int i = 0; i < 8; ++i) {
        const int idx = i * 64 + ln;
        const float4 wa = w0[idx];
        const float4 wb = w1[idx];
        const float4 xv = sx[idx];
        a0 += dot4(wa, xv);
        a1 += dot4(wb, xv);
    }
    a0 = wave_reduce(a0);
    a1 = wave_reduce(a1);
    if (ln == 0) {
        float* p = ws + (size_t)(2 + m) * MEM;
        p[row0]     = a0;
        p[row0 + 1] = a1;
    }
}

// k3: combine partials -> gates -> c, h. grid 8x256.
__global__ __launch_bounds__(256) void
k3_combine(const float* __restrict__ lc, const float* __restrict__ rc,
           const float* __restrict__ ilh_b,  const float* __restrict__ irh_b,
           const float* __restrict__ lflh_b, const float* __restrict__ lfrh_b,
           const float* __restrict__ rflh_b, const float* __restrict__ rfrh_b,
           const float* __restrict__ ulh_b,  const float* __restrict__ urh_b,
           const float* __restrict__ ws, float* __restrict__ out)
{
    const int j = blockIdx.x * 256 + threadIdx.x;
    const float* P = ws + 2 * MEM;
    const float gi = sigmoidf_(P[j]           + P[MEM + j]     + ilh_b[j]  + irh_b[j]);
    const float lf = sigmoidf_(P[2 * MEM + j] + P[3 * MEM + j] + lflh_b[j] + lfrh_b[j]);
    const float rf = sigmoidf_(P[4 * MEM + j] + P[5 * MEM + j] + rflh_b[j] + rfrh_b[j]);
    const float u  = tanhf(    P[6 * MEM + j] + P[7 * MEM + j] + ulh_b[j]  + urh_b[j]);
    const float c  = gi * u + lf * lc[j] + rf * rc[j];
    out[j]       = c;
    out[MEM + j] = tanhf(c);
}

extern "C" void kernel_launch(void* const* d_in, const int* in_sizes, int n_in,
                              void* d_out, int out_size, void* d_ws, size_t ws_size,
                              hipStream_t stream) {
    const float* lc = (const float*)d_in[0];
    const float* lh = (const float*)d_in[1];
    const float* rc = (const float*)d_in[2];
    const float* rh = (const float*)d_in[3];
    const float* S  = (const float*)d_in[4];
    const float* w  = (const float*)d_in[5];
    const float* Wh_w   = (const float*)d_in[6];   const float* Wh_b   = (const float*)d_in[7];
    const float* Us_w   = (const float*)d_in[8];   const float* Us_b   = (const float*)d_in[9];
    const float* ma_w   = (const float*)d_in[10];  const float* ma_b   = (const float*)d_in[11];
    const float* ilh_w  = (const float*)d_in[12];  const float* ilh_b  = (const float*)d_in[13];
    const float* irh_w  = (const float*)d_in[14];  const float* irh_b  = (const float*)d_in[15];
    const float* lflh_w = (const float*)d_in[16];  const float* lflh_b = (const float*)d_in[17];
    const float* lfrh_w = (const float*)d_in[18];  const float* lfrh_b = (const float*)d_in[19];
    const float* rflh_w = (const float*)d_in[20];  const float* rflh_b = (const float*)d_in[21];
    const float* rfrh_w = (const float*)d_in[22];  const float* rfrh_b = (const float*)d_in[23];
    const float* ulh_w  = (const float*)d_in[24];  const float* ulh_b  = (const float*)d_in[25];
    const float* urh_w  = (const float*)d_in[26];  const float* urh_b  = (const float*)d_in[27];

    float* out = (float*)d_out;
    float* ws  = (float*)d_ws;

    dim3 g1(256, 3);
    k1_slab<<<g1, 256, 0, stream>>>(lh, rh, S, Wh_w, Us_w, ma_w, ws);

    k_mid<<<1, 1024, 0, stream>>>(w, Wh_b, Us_b, ma_b, ws);

    dim3 g2(256, 8);
    k2_slab<<<g2, 256, 0, stream>>>(ilh_w, irh_w, lflh_w, lfrh_w,
                                    rflh_w, rfrh_w, ulh_w, urh_w, ws);

    k3_combine<<<8, 256, 0, stream>>>(lc, rc, ilh_b, irh_b, lflh_b, lfrh_b,
                                      rflh_b, rfrh_b, ulh_b, urh_b, ws, out);
}

// Round 4
// 249.405 us; speedup vs baseline: 1.0077x; 1.0077x over previous
//
#include <hip/hip_runtime.h>
#include <hip/hip_bf16.h>
#include <math.h>
#include <stdint.h>

#define MEM 2048
#define NF4 512   // float4 per 2048-row

__device__ __forceinline__ float dot4(float4 a, float4 b) {
    return a.x * b.x + a.y * b.y + a.z * b.z + a.w * b.w;
}

__device__ __forceinline__ float wave_reduce(float v) {
#pragma unroll
    for (int off = 32; off > 0; off >>= 1)
        v += __shfl_down(v, off, 64);
    return v;
}

__device__ __forceinline__ float sigmoidf_(float x) {
    return 1.0f / (1.0f + expf(-x));
}

// async 16B/lane global->LDS DMA: data lands at lds_base + lane*16.
// lds base must be wave-uniform; global address is per-lane.
__device__ __forceinline__ void dma16(const float* g, float* l) {
    __builtin_amdgcn_global_load_lds(
        (const __attribute__((address_space(1))) uint32_t*)(uintptr_t)(const void*)g,
        (__attribute__((address_space(3))) uint32_t*)(uintptr_t)(const void*)l,
        16, 0, 0);
}

template <int N>
__device__ __forceinline__ void wait_vmcnt() {
    asm volatile("s_waitcnt vmcnt(%0)" ::"n"(N) : "memory");
}

// ws layout (floats):
//  slot0 [0*2048): dwl (k1)  -> overwritten by la (k_mid)
//  slot1 [1*2048): dwr (k1)  -> overwritten by ra (k_mid)
//  slot2 [2*2048): dus (k1)  -> overwritten by part[m=0] (k2)
//  slot3 [3*2048): pl  (k1)  -> overwritten by part[m=1] (k2)
//  slot4 [4*2048): pr  (k1)  -> overwritten by part[m=2] (k2)
//  slot5..9      : part[m=3..7] (k2)

// k1: gridDim=(256,3). blockIdx.y: 0=Wh, 1=Us, 2=ma. Block = one contiguous
// 64KB slab (8 rows); wave = 2 rows. Triple-buffered global_load_lds staging,
// prefetch depth 2, per-wave vmcnt waits (no barriers in the chunk loop).
__global__ __launch_bounds__(256) void
k1_slab(const float* __restrict__ lh, const float* __restrict__ rh,
        const float* __restrict__ S,
        const float* __restrict__ Wh_w, const float* __restrict__ Us_w,
        const float* __restrict__ ma_w,
        float* __restrict__ ws)
{
    __shared__ __align__(16) float s_x1[MEM];
    __shared__ __align__(16) float s_x2[MEM];
    __shared__ __align__(16) float s_stg[4][3][2][256];  // wave, buf, row, 64*4

    const int t  = threadIdx.x;
    const int m  = blockIdx.y;
    const int rg = blockIdx.x;

    const float* W  = (m == 0) ? Wh_w : (m == 1) ? Us_w : ma_w;
    const float* x1 = (m == 1) ? S : lh;
    const float* x2 = (m == 1) ? S : rh;

    {
        const float4* a4 = (const float4*)x1;
        const float4* b4 = (const float4*)x2;
        float4* s14 = (float4*)s_x1;
        float4* s24 = (float4*)s_x2;
        for (int i = t; i < NF4; i += 256) { s14[i] = a4[i]; s24[i] = b4[i]; }
    }
    __syncthreads();

    const int wv = t >> 6, ln = t & 63;
    const int row0 = rg * 8 + wv * 2;

    const float* g0 = W + (size_t)row0 * MEM + ln * 4;
    const float* g1 = g0 + MEM;

    // prologue: stage chunks 0,1 into buffers 0,1 (4 DMAs outstanding)
    dma16(g0 + 0 * 256, &s_stg[wv][0][0][0]);
    dma16(g1 + 0 * 256, &s_stg[wv][0][1][0]);
    dma16(g0 + 1 * 256, &s_stg[wv][1][0][0]);
    dma16(g1 + 1 * 256, &s_stg[wv][1][1][0]);

    const float4* sx1 = (const float4*)s_x1;
    const float4* sx2 = (const float4*)s_x2;

    float a00 = 0.f, a01 = 0.f, a10 = 0.f, a11 = 0.f;
#pragma unroll
    for (int c = 0; c < 8; ++c) {
        if (c + 2 < 8) {
            const int nb = (c + 2) % 3;
            dma16(g0 + (c + 2) * 256, &s_stg[wv][nb][0][0]);
            dma16(g1 + (c + 2) * 256, &s_stg[wv][nb][1][0]);
            wait_vmcnt<4>();
        } else if (c + 1 < 8) {
            wait_vmcnt<2>();
        } else {
            wait_vmcnt<0>();
        }
        const int buf = c % 3;
        const float4 wa = ((const float4*)&s_stg[wv][buf][0][0])[ln];
        const float4 wb = ((const float4*)&s_stg[wv][buf][1][0])[ln];
        const float4 p  = sx1[c * 64 + ln];
        const float4 q  = sx2[c * 64 + ln];
        a00 += dot4(wa, p); a01 += dot4(wa, q);
        a10 += dot4(wb, p); a11 += dot4(wb, q);
    }
    a00 = wave_reduce(a00); a01 = wave_reduce(a01);
    a10 = wave_reduce(a10); a11 = wave_reduce(a11);

    if (ln == 0) {
        if (m == 0) {            // Wh: dwl = W·lh, dwr = W·rh
            ws[row0] = a00; ws[row0 + 1] = a10;
            ws[MEM + row0] = a01; ws[MEM + row0 + 1] = a11;
        } else if (m == 1) {     // Us: dus = W·S
            ws[2 * MEM + row0] = a00; ws[2 * MEM + row0 + 1] = a10;
        } else {                 // ma: pl = W·lh, pr = W·rh
            ws[3 * MEM + row0] = a00; ws[3 * MEM + row0 + 1] = a10;
            ws[4 * MEM + row0] = a01; ws[4 * MEM + row0 + 1] = a11;
        }
    }
}

// k_mid: ONE block. alpha from raw dots, then la/ra into ws slots 0/1.
__global__ __launch_bounds__(1024) void
k_mid(const float* __restrict__ w, const float* __restrict__ Wh_b,
      const float* __restrict__ Us_b, const float* __restrict__ ma_b,
      float* __restrict__ ws)
{
    __shared__ float s_red[16][2];
    __shared__ float s_al[2];

    const int t = threadIdx.x;
    float el = 0.f, er = 0.f;
    for (int j = t; j < MEM; j += 1024) {
        const float us = ws[2 * MEM + j] + Us_b[j];
        const float bb = Wh_b[j] + us;
        const float ml = tanhf(ws[j] + bb);
        const float mr = tanhf(ws[MEM + j] + bb);
        const float wj = w[j];
        el += wj * ml; er += wj * mr;
    }
    el = wave_reduce(el);
    er = wave_reduce(er);
    const int wv = t >> 6, ln = t & 63;
    if (ln == 0) { s_red[wv][0] = el; s_red[wv][1] = er; }
    __syncthreads();
    if (t == 0) {
        float e0 = 0.f, e1 = 0.f;
#pragma unroll
        for (int k = 0; k < 16; ++k) { e0 += s_red[k][0]; e1 += s_red[k][1]; }
        const float d = e0 + e1;
        s_al[0] = e0 / d;
        s_al[1] = e1 / d;
    }
    __syncthreads();
    const float al = s_al[0];
    const float ar = s_al[1];
    for (int j = t; j < MEM; j += 1024) {
        const float mb = ma_b[j];
        const float la = tanhf(al * ws[3 * MEM + j] + mb);
        const float ra = tanhf(ar * ws[4 * MEM + j] + mb);
        ws[j] = la;          // safe: this thread's dwl[j]/dwr[j] consumed pre-barrier
        ws[MEM + j] = ra;
    }
}

// k2: gridDim=(256,8). blockIdx.y = gate-matrix m (even→la, odd→ra).
// Block = one contiguous 64KB slab (8 rows); wave = 2 rows; triple-buffered
// global_load_lds staging, prefetch depth 2, per-wave vmcnt waits.
__global__ __launch_bounds__(256) void
k2_slab(const float* __restrict__ ilh_w,  const float* __restrict__ irh_w,
        const float* __restrict__ lflh_w, const float* __restrict__ lfrh_w,
        const float* __restrict__ rflh_w, const float* __restrict__ rfrh_w,
        const float* __restrict__ ulh_w,  const float* __restrict__ urh_w,
        float* __restrict__ ws)
{
    __shared__ __align__(16) float s_x[MEM];
    __shared__ __align__(16) float s_stg[4][3][2][256];  // wave, buf, row, 64*4

    const int t  = threadIdx.x;
    const int m  = blockIdx.y;
    const int rg = blockIdx.x;

    const float* Wt[8] = {ilh_w, irh_w, lflh_w, lfrh_w, rflh_w, rfrh_w, ulh_w, urh_w};
    const float* W = Wt[m];
    const float* x = ws + (size_t)(m & 1) * MEM;   // even=la, odd=ra

    {
        const float4* x4 = (const float4*)x;
        float4* s4 = (float4*)s_x;
        for (int i = t; i < NF4; i += 256) s4[i] = x4[i];
    }
    __syncthreads();

    const int wv = t >> 6, ln = t & 63;
    const int row0 = rg * 8 + wv * 2;

    const float* g0 = W + (size_t)row0 * MEM + ln * 4;
    const float* g1 = g0 + MEM;

    dma16(g0 + 0 * 256, &s_stg[wv][0][0][0]);
    dma16(g1 + 0 * 256, &s_stg[wv][0][1][0]);
    dma16(g0 + 1 * 256, &s_stg[wv][1][0][0]);
    dma16(g1 + 1 * 256, &s_stg[wv][1][1][0]);

    const float4* sx = (const float4*)s_x;

    float a0 = 0.f, a1 = 0.f;
#pragma unroll
    for (int c = 0; c < 8; ++c) {
        if (c + 2 < 8) {
            const int nb = (c + 2) % 3;
            dma16(g0 + (c + 2) * 256, &s_stg[wv][nb][0][0]);
            dma16(g1 + (c + 2) * 256, &s_stg[wv][nb][1][0]);
            wait_vmcnt<4>();
        } else if (c + 1 < 8) {
            wait_vmcnt<2>();
        } else {
            wait_vmcnt<0>();
        }
        const int buf = c % 3;
        const float4 wa = ((const float4*)&s_stg[wv][buf][0][0])[ln];
        const float4 wb = ((const float4*)&s_stg[wv][buf][1][0])[ln];
        const float4 xv = sx[c * 64 + ln];
        a0 += dot4(wa, xv);
        a1 += dot4(wb, xv);
    }
    a0 = wave_reduce(a0);
    a1 = wave_reduce(a1);
    if (ln == 0) {
        float* p = ws + (size_t)(2 + m) * MEM;
        p[row0]     = a0;
        p[row0 + 1] = a1;
    }
}

// k3: combine partials -> gates -> c, h. grid 8x256.
__global__ __launch_bounds__(256) void
k3_combine(const float* __restrict__ lc, const float* __restrict__ rc,
           const float* __restrict__ ilh_b,  const float* __restrict__ irh_b,
           const float* __restrict__ lflh_b, const float* __restrict__ lfrh_b,
           const float* __restrict__ rflh_b, const float* __restrict__ rfrh_b,
           const float* __restrict__ ulh_b,  const float* __restrict__ urh_b,
           const float* __restrict__ ws, float* __restrict__ out)
{
    const int j = blockIdx.x * 256 + threadIdx.x;
    const float* P = ws + 2 * MEM;
    const float gi = sigmoidf_(P[j]           + P[MEM + j]     + ilh_b[j]  + irh_b[j]);
    const float lf = sigmoidf_(P[2 * MEM + j] + P[3 * MEM + j] + lflh_b[j] + lfrh_b[j]);
    const float rf = sigmoidf_(P[4 * MEM + j] + P[5 * MEM + j] + rflh_b[j] + rfrh_b[j]);
    const float u  = tanhf(    P[6 * MEM + j] + P[7 * MEM + j] + ulh_b[j]  + urh_b[j]);
    const float c  = gi * u + lf * lc[j] + rf * rc[j];
    out[j]       = c;
    out[MEM + j] = tanhf(c);
}

extern "C" void kernel_launch(void* const* d_in, const int* in_sizes, int n_in,
                              void* d_out, int out_size, void* d_ws, size_t ws_size,
                              hipStream_t stream) {
    const float* lc = (const float*)d_in[0];
    const float* lh = (const float*)d_in[1];
    const float* rc = (const float*)d_in[2];
    const float* rh = (const float*)d_in[3];
    const float* S  = (const float*)d_in[4];
    const float* w  = (const float*)d_in[5];
    const float* Wh_w   = (const float*)d_in[6];   const float* Wh_b   = (const float*)d_in[7];
    const float* Us_w   = (const float*)d_in[8];   const float* Us_b   = (const float*)d_in[9];
    const float* ma_w   = (const float*)d_in[10];  const float* ma_b   = (const float*)d_in[11];
    const float* ilh_w  = (const float*)d_in[12];  const float* ilh_b  = (const float*)d_in[13];
    const float* irh_w  = (const float*)d_in[14];  const float* irh_b  = (const float*)d_in[15];
    const float* lflh_w = (const float*)d_in[16];  const float* lflh_b = (const float*)d_in[17];
    const float* lfrh_w = (const float*)d_in[18];  const float* lfrh_b = (const float*)d_in[19];
    const float* rflh_w = (const float*)d_in[20];  const float* rflh_b = (const float*)d_in[21];
    const float* rfrh_w = (const float*)d_in[22];  const float* rfrh_b = (const float*)d_in[23];
    const float* ulh_w  = (const float*)d_in[24];  const float* ulh_b  = (const float*)d_in[25];
    const float* urh_w  = (const float*)d_in[26];  const float* urh_b  = (const float*)d_in[27];

    float* out = (float*)d_out;
    float* ws  = (float*)d_ws;

    dim3 g1(256, 3);
    k1_slab<<<g1, 256, 0, stream>>>(lh, rh, S, Wh_w, Us_w, ma_w, ws);

    k_mid<<<1, 1024, 0, stream>>>(w, Wh_b, Us_b, ma_b, ws);

    dim3 g2(256, 8);
    k2_slab<<<g2, 256, 0, stream>>>(ilh_w, irh_w, lflh_w, lfrh_w,
                                    rflh_w, rfrh_w, ulh_w, urh_w, ws);

    k3_combine<<<8, 256, 0, stream>>>(lc, rc, ilh_b, irh_b, lflh_b, lfrh_b,
                                      rflh_b, rfrh_b, ulh_b, urh_b, ws, out);
}

// Round 5
// 247.164 us; speedup vs baseline: 1.0169x; 1.0091x over previous
//
#include <hip/hip_runtime.h>
#include <hip/hip_bf16.h>
#include <math.h>

#define MEM 2048
#define NF4 512   // float4 per 2048-row

__device__ __forceinline__ float dot4(float4 a, float4 b) {
    return a.x * b.x + a.y * b.y + a.z * b.z + a.w * b.w;
}

__device__ __forceinline__ float wave_reduce(float v) {
#pragma unroll
    for (int off = 32; off > 0; off >>= 1)
        v += __shfl_down(v, off, 64);
    return v;
}

__device__ __forceinline__ float sigmoidf_(float x) {
    return 1.0f / (1.0f + expf(-x));
}

// ws layout (floats):
//  slot0 [0*2048): dwl (k1)  -> overwritten by la (k_mid)
//  slot1 [1*2048): dwr (k1)  -> overwritten by ra (k_mid)
//  slot2 [2*2048): dus (k1)  -> overwritten by part[m=0] (k2)
//  slot3 [3*2048): pl  (k1)  -> overwritten by part[m=1] (k2)
//  slot4 [4*2048): pr  (k1)  -> overwritten by part[m=2] (k2)
//  slot5..9      : part[m=3..7] (k2)

// k1: gridDim=(256,3). m: 0=Wh, 1=Us, 2=ma. Block = one contiguous 64KB slab
// (8 rows); wave = 2 rows. The wave's entire 16KB slab is loaded into
// registers as 16 independent float4 loads (deep MLP), then dotted against
// the LDS-resident x-vectors.
__global__ __launch_bounds__(256, 4) void
k1_slab(const float* __restrict__ lh, const float* __restrict__ rh,
        const float* __restrict__ S,
        const float* __restrict__ Wh_w, const float* __restrict__ Us_w,
        const float* __restrict__ ma_w,
        float* __restrict__ ws)
{
    __shared__ __align__(16) float s_x1[MEM];
    __shared__ __align__(16) float s_x2[MEM];

    const int t  = threadIdx.x;
    const int m  = blockIdx.y;
    const int rg = blockIdx.x;

    const float* W  = (m == 0) ? Wh_w : (m == 1) ? Us_w : ma_w;
    const float* x1 = (m == 1) ? S : lh;
    const float* x2 = (m == 1) ? S : rh;

    {
        const float4* a4 = (const float4*)x1;
        const float4* b4 = (const float4*)x2;
        float4* s14 = (float4*)s_x1;
        float4* s24 = (float4*)s_x2;
        for (int i = t; i < NF4; i += 256) { s14[i] = a4[i]; s24[i] = b4[i]; }
    }
    __syncthreads();

    const int wv = t >> 6, ln = t & 63;
    const int row0 = rg * 8 + wv * 2;

    const float4* __restrict__ w0 = (const float4*)(W + (size_t)row0 * MEM);
    const float4* __restrict__ w1 = w0 + NF4;
    const float4* sx1 = (const float4*)s_x1;
    const float4* sx2 = (const float4*)s_x2;

    // issue all 16 weight loads (2 rows x 8 chunks) before any use
    float4 A[8], B[8];
#pragma unroll
    for (int j = 0; j < 8; ++j) A[j] = w0[j * 64 + ln];
#pragma unroll
    for (int j = 0; j < 8; ++j) B[j] = w1[j * 64 + ln];

    float a00 = 0.f, a01 = 0.f, a10 = 0.f, a11 = 0.f;
#pragma unroll
    for (int j = 0; j < 8; ++j) {
        const float4 p = sx1[j * 64 + ln];
        const float4 q = sx2[j * 64 + ln];
        a00 += dot4(A[j], p); a01 += dot4(A[j], q);
        a10 += dot4(B[j], p); a11 += dot4(B[j], q);
    }
    a00 = wave_reduce(a00); a01 = wave_reduce(a01);
    a10 = wave_reduce(a10); a11 = wave_reduce(a11);

    if (ln == 0) {
        if (m == 0) {            // Wh: dwl = W·lh, dwr = W·rh
            ws[row0] = a00; ws[row0 + 1] = a10;
            ws[MEM + row0] = a01; ws[MEM + row0 + 1] = a11;
        } else if (m == 1) {     // Us: dus = W·S
            ws[2 * MEM + row0] = a00; ws[2 * MEM + row0 + 1] = a10;
        } else {                 // ma: pl = W·lh, pr = W·rh
            ws[3 * MEM + row0] = a00; ws[3 * MEM + row0 + 1] = a10;
            ws[4 * MEM + row0] = a01; ws[4 * MEM + row0 + 1] = a11;
        }
    }
}

// k_mid: ONE block. alpha from raw dots, then la/ra into ws slots 0/1.
__global__ __launch_bounds__(1024) void
k_mid(const float* __restrict__ w, const float* __restrict__ Wh_b,
      const float* __restrict__ Us_b, const float* __restrict__ ma_b,
      float* __restrict__ ws)
{
    __shared__ float s_red[16][2];
    __shared__ float s_al[2];

    const int t = threadIdx.x;
    float el = 0.f, er = 0.f;
    for (int j = t; j < MEM; j += 1024) {
        const float us = ws[2 * MEM + j] + Us_b[j];
        const float bb = Wh_b[j] + us;
        const float ml = tanhf(ws[j] + bb);
        const float mr = tanhf(ws[MEM + j] + bb);
        const float wj = w[j];
        el += wj * ml; er += wj * mr;
    }
    el = wave_reduce(el);
    er = wave_reduce(er);
    const int wv = t >> 6, ln = t & 63;
    if (ln == 0) { s_red[wv][0] = el; s_red[wv][1] = er; }
    __syncthreads();
    if (t == 0) {
        float e0 = 0.f, e1 = 0.f;
#pragma unroll
        for (int k = 0; k < 16; ++k) { e0 += s_red[k][0]; e1 += s_red[k][1]; }
        const float d = e0 + e1;
        s_al[0] = e0 / d;
        s_al[1] = e1 / d;
    }
    __syncthreads();
    const float al = s_al[0];
    const float ar = s_al[1];
    for (int j = t; j < MEM; j += 1024) {
        const float mb = ma_b[j];
        const float la = tanhf(al * ws[3 * MEM + j] + mb);
        const float ra = tanhf(ar * ws[4 * MEM + j] + mb);
        ws[j] = la;          // safe: this thread's dwl[j]/dwr[j] consumed pre-barrier
        ws[MEM + j] = ra;
    }
}

// k2: gridDim=(256,8). blockIdx.y = gate-matrix m (even→la, odd→ra).
// Block = one contiguous 64KB slab (8 rows); wave = 2 rows, whole 16KB slab
// loaded into registers (16 independent float4 loads) before compute.
__global__ __launch_bounds__(256, 4) void
k2_slab(const float* __restrict__ ilh_w,  const float* __restrict__ irh_w,
        const float* __restrict__ lflh_w, const float* __restrict__ lfrh_w,
        const float* __restrict__ rflh_w, const float* __restrict__ rfrh_w,
        const float* __restrict__ ulh_w,  const float* __restrict__ urh_w,
        float* __restrict__ ws)
{
    __shared__ __align__(16) float s_x[MEM];

    const int t  = threadIdx.x;
    const int m  = blockIdx.y;
    const int rg = blockIdx.x;

    const float* Wt[8] = {ilh_w, irh_w, lflh_w, lfrh_w, rflh_w, rfrh_w, ulh_w, urh_w};
    const float* W = Wt[m];
    const float* x = ws + (size_t)(m & 1) * MEM;   // even=la, odd=ra

    {
        const float4* x4 = (const float4*)x;
        float4* s4 = (float4*)s_x;
        for (int i = t; i < NF4; i += 256) s4[i] = x4[i];
    }
    __syncthreads();

    const int wv = t >> 6, ln = t & 63;
    const int row0 = rg * 8 + wv * 2;

    const float4* __restrict__ w0 = (const float4*)(W + (size_t)row0 * MEM);
    const float4* __restrict__ w1 = w0 + NF4;
    const float4* sx = (const float4*)s_x;

    float4 A[8], B[8];
#pragma unroll
    for (int j = 0; j < 8; ++j) A[j] = w0[j * 64 + ln];
#pragma unroll
    for (int j = 0; j < 8; ++j) B[j] = w1[j * 64 + ln];

    float a0 = 0.f, a1 = 0.f;
#pragma unroll
    for (int j = 0; j < 8; ++j) {
        const float4 xv = sx[j * 64 + ln];
        a0 += dot4(A[j], xv);
        a1 += dot4(B[j], xv);
    }
    a0 = wave_reduce(a0);
    a1 = wave_reduce(a1);
    if (ln == 0) {
        float* p = ws + (size_t)(2 + m) * MEM;
        p[row0]     = a0;
        p[row0 + 1] = a1;
    }
}

// k3: combine partials -> gates -> c, h. grid 8x256.
__global__ __launch_bounds__(256) void
k3_combine(const float* __restrict__ lc, const float* __restrict__ rc,
           const float* __restrict__ ilh_b,  const float* __restrict__ irh_b,
           const float* __restrict__ lflh_b, const float* __restrict__ lfrh_b,
           const float* __restrict__ rflh_b, const float* __restrict__ rfrh_b,
           const float* __restrict__ ulh_b,  const float* __restrict__ urh_b,
           const float* __restrict__ ws, float* __restrict__ out)
{
    const int j = blockIdx.x * 256 + threadIdx.x;
    const float* P = ws + 2 * MEM;
    const float gi = sigmoidf_(P[j]           + P[MEM + j]     + ilh_b[j]  + irh_b[j]);
    const float lf = sigmoidf_(P[2 * MEM + j] + P[3 * MEM + j] + lflh_b[j] + lfrh_b[j]);
    const float rf = sigmoidf_(P[4 * MEM + j] + P[5 * MEM + j] + rflh_b[j] + rfrh_b[j]);
    const float u  = tanhf(    P[6 * MEM + j] + P[7 * MEM + j] + ulh_b[j]  + urh_b[j]);
    const float c  = gi * u + lf * lc[j] + rf * rc[j];
    out[j]       = c;
    out[MEM + j] = tanhf(c);
}

extern "C" void kernel_launch(void* const* d_in, const int* in_sizes, int n_in,
                              void* d_out, int out_size, void* d_ws, size_t ws_size,
                              hipStream_t stream) {
    const float* lc = (const float*)d_in[0];
    const float* lh = (const float*)d_in[1];
    const float* rc = (const float*)d_in[2];
    const float* rh = (const float*)d_in[3];
    const float* S  = (const float*)d_in[4];
    const float* w  = (const float*)d_in[5];
    const float* Wh_w   = (const float*)d_in[6];   const float* Wh_b   = (const float*)d_in[7];
    const float* Us_w   = (const float*)d_in[8];   const float* Us_b   = (const float*)d_in[9];
    const float* ma_w   = (const float*)d_in[10];  const float* ma_b   = (const float*)d_in[11];
    const float* ilh_w  = (const float*)d_in[12];  const float* ilh_b  = (const float*)d_in[13];
    const float* irh_w  = (const float*)d_in[14];  const float* irh_b  = (const float*)d_in[15];
    const float* lflh_w = (const float*)d_in[16];  const float* lflh_b = (const float*)d_in[17];
    const float* lfrh_w = (const float*)d_in[18];  const float* lfrh_b = (const float*)d_in[19];
    const float* rflh_w = (const float*)d_in[20];  const float* rflh_b = (const float*)d_in[21];
    const float* rfrh_w = (const float*)d_in[22];  const float* rfrh_b = (const float*)d_in[23];
    const float* ulh_w  = (const float*)d_in[24];  const float* ulh_b  = (const float*)d_in[25];
    const float* urh_w  = (const float*)d_in[26];  const float* urh_b  = (const float*)d_in[27];

    float* out = (float*)d_out;
    float* ws  = (float*)d_ws;

    dim3 g1(256, 3);
    k1_slab<<<g1, 256, 0, stream>>>(lh, rh, S, Wh_w, Us_w, ma_w, ws);

    k_mid<<<1, 1024, 0, stream>>>(w, Wh_b, Us_b, ma_b, ws);

    dim3 g2(256, 8);
    k2_slab<<<g2, 256, 0, stream>>>(ilh_w, irh_w, lflh_w, lfrh_w,
                                    rflh_w, rfrh_w, ulh_w, urh_w, ws);

    k3_combine<<<8, 256, 0, stream>>>(lc, rc, ilh_b, irh_b, lflh_b, lfrh_b,
                                      rflh_b, rfrh_b, ulh_b, urh_b, ws, out);
}